// Round 3
// baseline (278.594 us; speedup 1.0000x reference)
//
#include <hip/hip_runtime.h>

#define CCC_EPS 1e-8
#define SEGS 4           // blocks per row
#define TPB 256
#define PER_THREAD 16    // vec4 per array per thread (SEGS*TPB*PER_THREAD*4 == T)

typedef float floatx4 __attribute__((ext_vector_type(4)));

// Grid: 2048 blocks. Each block reduces a contiguous 4096-vec4 segment of one
// row.
//
// Round-3 (= Round-2 resubmit; container infra failure, kernel never ran):
// plain (temporal) loads instead of __builtin_nontemporal_load.
// Evidence: fills WRITE at 6.8 TB/s, but this kernel READS at only ~3.6 TB/s.
// VALU demand is 20x under the HBM share, and in-flight-bytes arithmetic shows
// even a 2-deep load pipeline x16 waves/CU covers the latency-BW product 3x —
// so neither compute nor MLP explains the gap. The untested variable is the NT
// load path itself (no measurement anywhere shows NT reads at full rate; m13's
// 6.29 TB/s is read+write combined). NT's claimed benefit (L3 thrash) is nil
// for a single-pass stream with poison fills flushing L3 between iterations.
__global__ __launch_bounds__(TPB, 4) void ccc_partial_kernel(
    const float* __restrict__ preds,
    const float* __restrict__ labels,
    float* __restrict__ partial,   // [B*SEGS*5]
    int T)
{
    const int seg = blockIdx.x & (SEGS - 1);
    const int row = blockIdx.x >> 2;                 // SEGS == 4
    const int seg4 = (T >> 2) / SEGS;                // 4096 vec4
    const size_t base4 = (size_t)row * (size_t)(T >> 2) + (size_t)seg * seg4;
    const floatx4* __restrict__ p4 = (const floatx4*)preds + base4;
    const floatx4* __restrict__ l4 = (const floatx4*)labels + base4;

    float sx = 0.f, sy = 0.f, sxx = 0.f, syy = 0.f, sxy = 0.f;

    #pragma unroll 8
    for (int k = 0; k < PER_THREAD; ++k) {
        const int i = threadIdx.x + k * TPB;
        floatx4 x = p4[i];
        floatx4 y = l4[i];
        sx  += x.x + x.y + x.z + x.w;
        sy  += y.x + y.y + y.z + y.w;
        sxx = fmaf(x.x, x.x, sxx); sxx = fmaf(x.y, x.y, sxx);
        sxx = fmaf(x.z, x.z, sxx); sxx = fmaf(x.w, x.w, sxx);
        syy = fmaf(y.x, y.x, syy); syy = fmaf(y.y, y.y, syy);
        syy = fmaf(y.z, y.z, syy); syy = fmaf(y.w, y.w, syy);
        sxy = fmaf(x.x, y.x, sxy); sxy = fmaf(x.y, y.y, sxy);
        sxy = fmaf(x.z, y.z, sxy); sxy = fmaf(x.w, y.w, sxy);
    }

    // 64-lane wave reduction
    #pragma unroll
    for (int off = 32; off > 0; off >>= 1) {
        sx  += __shfl_down(sx,  off);
        sy  += __shfl_down(sy,  off);
        sxx += __shfl_down(sxx, off);
        syy += __shfl_down(syy, off);
        sxy += __shfl_down(sxy, off);
    }

    __shared__ float red[4][5];
    const int wave = threadIdx.x >> 6;
    const int lane = threadIdx.x & 63;
    if (lane == 0) {
        red[wave][0] = sx;  red[wave][1] = sy;  red[wave][2] = sxx;
        red[wave][3] = syy; red[wave][4] = sxy;
    }
    __syncthreads();

    if (threadIdx.x == 0) {
        float t0 = red[0][0] + red[1][0] + red[2][0] + red[3][0];
        float t1 = red[0][1] + red[1][1] + red[2][1] + red[3][1];
        float t2 = red[0][2] + red[1][2] + red[2][2] + red[3][2];
        float t3 = red[0][3] + red[1][3] + red[2][3] + red[3][3];
        float t4 = red[0][4] + red[1][4] + red[2][4] + red[3][4];
        float* dst = partial + ((size_t)row * SEGS + seg) * 5;
        dst[0] = t0; dst[1] = t1; dst[2] = t2; dst[3] = t3; dst[4] = t4;
    }
}

// Single block: one thread per row combines its SEGS partials in double,
// computes (1 - ccc), then block-reduces the mean.
__global__ __launch_bounds__(512) void ccc_final_kernel(
    const float* __restrict__ partial,
    float* __restrict__ out,
    int B, int T)
{
    float loss_sum = 0.f;
    for (int b = threadIdx.x; b < B; b += 512) {
        double tsx = 0, tsy = 0, tsxx = 0, tsyy = 0, tsxy = 0;
        const float* src = partial + (size_t)b * SEGS * 5;
        #pragma unroll
        for (int s = 0; s < SEGS; ++s) {
            tsx  += src[s * 5 + 0];
            tsy  += src[s * 5 + 1];
            tsxx += src[s * 5 + 2];
            tsyy += src[s * 5 + 3];
            tsxy += src[s * 5 + 4];
        }
        const double inv = 1.0 / (double)T;
        const double mx = tsx * inv;
        const double my = tsy * inv;
        const double vx = tsxx * inv - mx * mx;
        const double vy = tsyy * inv - my * my;
        const double cov = tsxy * inv - mx * my;
        const double d = mx - my;
        const double ccc = 2.0 * cov / (vx + vy + d * d + CCC_EPS);
        loss_sum += (float)(1.0 - ccc);
    }

    #pragma unroll
    for (int off = 32; off > 0; off >>= 1) loss_sum += __shfl_down(loss_sum, off);

    __shared__ float red[8];
    const int wave = threadIdx.x >> 6;
    const int lane = threadIdx.x & 63;
    if (lane == 0) red[wave] = loss_sum;
    __syncthreads();
    if (threadIdx.x == 0) {
        float t = 0.f;
        #pragma unroll
        for (int w = 0; w < 8; ++w) t += red[w];
        out[0] = t / (float)B;
    }
}

extern "C" void kernel_launch(void* const* d_in, const int* in_sizes, int n_in,
                              void* d_out, int out_size, void* d_ws, size_t ws_size,
                              hipStream_t stream) {
    const float* preds  = (const float*)d_in[0];
    const float* labels = (const float*)d_in[1];
    float* out = (float*)d_out;

    const int T = 65536;
    const int B = in_sizes[0] / T;   // 512

    float* partial = (float*)d_ws;   // B*SEGS*5 floats

    ccc_partial_kernel<<<B * SEGS, TPB, 0, stream>>>(preds, labels, partial, T);
    ccc_final_kernel<<<1, 512, 0, stream>>>(partial, out, B, T);
}

// Round 4
// 249.147 us; speedup vs baseline: 1.1182x; 1.1182x over previous
//
#include <hip/hip_runtime.h>

#define CCC_EPS 1e-8
#define SEGS 4           // blocks per row
#define TPB 256
#define PER_THREAD 16    // vec4 per array per thread (SEGS*TPB*PER_THREAD*4 == T)

typedef float floatx4 __attribute__((ext_vector_type(4)));

// Round-4: NT loads (reverted — round-3 A/B proved temporal loads are WORSE:
// 50% L3 hit rate yet 107 vs 79 us, alloc/thrash costs more than hits give)
// + explicit 16-deep load staging. Round-3's VGPR_Count=20 revealed the
// compiler never pipelined the loads: one x/y pair in flight per wave
// (2 KB) must cover ~900 cy HBM latency -> per-CU read stream capped at
// ~3.4 TB/s while the response-less fill WRITES stream at 6.8 TB/s with 3
// waves/CU. Fix: stage 8+8 vec4 loads into named registers before consuming
// (16 KB/wave in flight, 32 outstanding dwordx4 < vmcnt cap 63). Consumption
// order per k is unchanged -> bit-identical accumulation (absmax 0.0).
// LB(256,4) gives the 128-VGPR budget this ~90-reg working set needs.
__global__ __launch_bounds__(TPB, 4) void ccc_partial_kernel(
    const float* __restrict__ preds,
    const float* __restrict__ labels,
    float* __restrict__ partial,   // [B*SEGS*5]
    int T)
{
    const int seg = blockIdx.x & (SEGS - 1);
    const int row = blockIdx.x >> 2;                 // SEGS == 4
    const int seg4 = (T >> 2) / SEGS;                // 4096 vec4
    const size_t base4 = (size_t)row * (size_t)(T >> 2) + (size_t)seg * seg4;
    const floatx4* __restrict__ p4 = (const floatx4*)preds + base4;
    const floatx4* __restrict__ l4 = (const floatx4*)labels + base4;

    float sx = 0.f, sy = 0.f, sxx = 0.f, syy = 0.f, sxy = 0.f;

    #pragma unroll
    for (int kk = 0; kk < PER_THREAD; kk += 8) {
        // Phase 1: issue all 16 loads (compile-time-indexed array, fully
        // unrolled -> stays in registers, no scratch).
        floatx4 xs[8], ys[8];
        #pragma unroll
        for (int j = 0; j < 8; ++j) {
            const int i = threadIdx.x + (kk + j) * TPB;
            xs[j] = __builtin_nontemporal_load(&p4[i]);
            ys[j] = __builtin_nontemporal_load(&l4[i]);
        }
        // Phase 2: consume in the ORIGINAL k order (bit-identical FP chain).
        #pragma unroll
        for (int j = 0; j < 8; ++j) {
            floatx4 x = xs[j];
            floatx4 y = ys[j];
            sx  += x.x + x.y + x.z + x.w;
            sy  += y.x + y.y + y.z + y.w;
            sxx = fmaf(x.x, x.x, sxx); sxx = fmaf(x.y, x.y, sxx);
            sxx = fmaf(x.z, x.z, sxx); sxx = fmaf(x.w, x.w, sxx);
            syy = fmaf(y.x, y.x, syy); syy = fmaf(y.y, y.y, syy);
            syy = fmaf(y.z, y.z, syy); syy = fmaf(y.w, y.w, syy);
            sxy = fmaf(x.x, y.x, sxy); sxy = fmaf(x.y, y.y, sxy);
            sxy = fmaf(x.z, y.z, sxy); sxy = fmaf(x.w, y.w, sxy);
        }
    }

    // 64-lane wave reduction
    #pragma unroll
    for (int off = 32; off > 0; off >>= 1) {
        sx  += __shfl_down(sx,  off);
        sy  += __shfl_down(sy,  off);
        sxx += __shfl_down(sxx, off);
        syy += __shfl_down(syy, off);
        sxy += __shfl_down(sxy, off);
    }

    __shared__ float red[4][5];
    const int wave = threadIdx.x >> 6;
    const int lane = threadIdx.x & 63;
    if (lane == 0) {
        red[wave][0] = sx;  red[wave][1] = sy;  red[wave][2] = sxx;
        red[wave][3] = syy; red[wave][4] = sxy;
    }
    __syncthreads();

    if (threadIdx.x == 0) {
        float t0 = red[0][0] + red[1][0] + red[2][0] + red[3][0];
        float t1 = red[0][1] + red[1][1] + red[2][1] + red[3][1];
        float t2 = red[0][2] + red[1][2] + red[2][2] + red[3][2];
        float t3 = red[0][3] + red[1][3] + red[2][3] + red[3][3];
        float t4 = red[0][4] + red[1][4] + red[2][4] + red[3][4];
        float* dst = partial + ((size_t)row * SEGS + seg) * 5;
        dst[0] = t0; dst[1] = t1; dst[2] = t2; dst[3] = t3; dst[4] = t4;
    }
}

// Single block: one thread per row combines its SEGS partials in double,
// computes (1 - ccc), then block-reduces the mean.
__global__ __launch_bounds__(512) void ccc_final_kernel(
    const float* __restrict__ partial,
    float* __restrict__ out,
    int B, int T)
{
    float loss_sum = 0.f;
    for (int b = threadIdx.x; b < B; b += 512) {
        double tsx = 0, tsy = 0, tsxx = 0, tsyy = 0, tsxy = 0;
        const float* src = partial + (size_t)b * SEGS * 5;
        #pragma unroll
        for (int s = 0; s < SEGS; ++s) {
            tsx  += src[s * 5 + 0];
            tsy  += src[s * 5 + 1];
            tsxx += src[s * 5 + 2];
            tsyy += src[s * 5 + 3];
            tsxy += src[s * 5 + 4];
        }
        const double inv = 1.0 / (double)T;
        const double mx = tsx * inv;
        const double my = tsy * inv;
        const double vx = tsxx * inv - mx * mx;
        const double vy = tsyy * inv - my * my;
        const double cov = tsxy * inv - mx * my;
        const double d = mx - my;
        const double ccc = 2.0 * cov / (vx + vy + d * d + CCC_EPS);
        loss_sum += (float)(1.0 - ccc);
    }

    #pragma unroll
    for (int off = 32; off > 0; off >>= 1) loss_sum += __shfl_down(loss_sum, off);

    __shared__ float red[8];
    const int wave = threadIdx.x >> 6;
    const int lane = threadIdx.x & 63;
    if (lane == 0) red[wave] = loss_sum;
    __syncthreads();
    if (threadIdx.x == 0) {
        float t = 0.f;
        #pragma unroll
        for (int w = 0; w < 8; ++w) t += red[w];
        out[0] = t / (float)B;
    }
}

extern "C" void kernel_launch(void* const* d_in, const int* in_sizes, int n_in,
                              void* d_out, int out_size, void* d_ws, size_t ws_size,
                              hipStream_t stream) {
    const float* preds  = (const float*)d_in[0];
    const float* labels = (const float*)d_in[1];
    float* out = (float*)d_out;

    const int T = 65536;
    const int B = in_sizes[0] / T;   // 512

    float* partial = (float*)d_ws;   // B*SEGS*5 floats

    ccc_partial_kernel<<<B * SEGS, TPB, 0, stream>>>(preds, labels, partial, T);
    ccc_final_kernel<<<1, 512, 0, stream>>>(partial, out, B, T);
}

// Round 5
// 246.132 us; speedup vs baseline: 1.1319x; 1.0123x over previous
//
#include <hip/hip_runtime.h>
#include <stdint.h>

#define CCC_EPS 1e-8
#define SEGS 4           // blocks per row
#define TPB 256
#define PER_THREAD 16    // vec4 per array per thread (SEGS*TPB*PER_THREAD*4 == T)
#define DEPTH 8          // LDS ring slots per wave per array
#define AHEAD 6          // DMA issue distance (slots ahead of consumption)

typedef float floatx4 __attribute__((ext_vector_type(4)));

// Round-5: route reads through the LDS-DMA path (global_load_lds) instead of
// the VGPR-return path. Eliminated so far: occupancy (R1 null), temporal
// caching (R3 negative, L2/L3 thrash), per-wave load depth (R4 null: 32
// outstanding dwordx4/wave did nothing). All data fits one model: writes
// (no response tracking) stream at 6.8 TB/s; reads cap at ~3.4 TB/s at ANY
// occupancy/depth => the per-CU vector-return/miss-tracking structure is the
// limiter (~4-5 KB of in-flight lines/CU vs the ~9 KB needed for 6.3 TB/s).
// global_load_lds completes into LDS, bypassing the per-lane return queue —
// the one untested read mechanism.
//
// Structure: per-wave private 8-slot ring in LDS, barrier-free (each wave
// consumes only what it DMA'd), issue 6 slots ahead, counted s_waitcnt
// vmcnt(12) — never drain to 0 in the main loop. Each lane DMAs exactly the
// 16 B it would have loaded and consumes in the original k order =>
// bit-identical accumulation (absmax 0.0). aux=2 = CPol NT (R3 proved
// temporal allocation is a net loss for this single-pass stream).
template <int N>
__device__ __forceinline__ void wait_vmcnt() {
    asm volatile("s_waitcnt vmcnt(%0)" :: "n"(N) : "memory");
}

__device__ __forceinline__ void gld_lds16(const void* g, void* l) {
    __builtin_amdgcn_global_load_lds(
        (const __attribute__((address_space(1))) uint32_t*)(uintptr_t)g,
        (__attribute__((address_space(3))) uint32_t*)(uint32_t)(uintptr_t)l,
        16, 0, 2 /* CPol: NT */);
}

__global__ __launch_bounds__(TPB, 4) void ccc_partial_kernel(
    const float* __restrict__ preds,
    const float* __restrict__ labels,
    float* __restrict__ partial,   // [B*SEGS*5]
    int T)
{
    const int seg = blockIdx.x & (SEGS - 1);
    const int row = blockIdx.x >> 2;                 // SEGS == 4
    const int seg4 = (T >> 2) / SEGS;                // 4096 vec4
    const size_t base4 = (size_t)row * (size_t)(T >> 2) + (size_t)seg * seg4;
    const floatx4* __restrict__ p4 = (const floatx4*)preds + base4;
    const floatx4* __restrict__ l4 = (const floatx4*)labels + base4;

    // Per-wave private staging rings: [wave][slot][lane] of 16B. 64 KB total
    // -> 2 blocks/CU (128 of 160 KB LDS).
    __shared__ floatx4 lx[4][DEPTH][64];
    __shared__ floatx4 ly[4][DEPTH][64];

    const int wave = threadIdx.x >> 6;
    const int lane = threadIdx.x & 63;

    float sx = 0.f, sy = 0.f, sxx = 0.f, syy = 0.f, sxy = 0.f;

    // DMA slot s: lane L of wave w sources p4/l4[s*TPB + w*64 + L] (== the
    // element thread (w,L) consumed in the original kernel at k=s) and lands
    // at ring[w][s&7] + L*16 (HW appends lane*size to the wave-uniform base).
#define ISSUE(s)                                                              \
    do {                                                                      \
        if ((s) < PER_THREAD) {                                               \
            const int _sl = (s) & (DEPTH - 1);                                \
            gld_lds16(&p4[(size_t)(s) * TPB + threadIdx.x], &lx[wave][_sl][0]); \
            gld_lds16(&l4[(size_t)(s) * TPB + threadIdx.x], &ly[wave][_sl][0]); \
        }                                                                     \
    } while (0)

#define CONSUME(k)                                                            \
    do {                                                                      \
        const int _sl = (k) & (DEPTH - 1);                                    \
        floatx4 x = lx[wave][_sl][lane];                                      \
        floatx4 y = ly[wave][_sl][lane];                                      \
        sx  += x.x + x.y + x.z + x.w;                                         \
        sy  += y.x + y.y + y.z + y.w;                                         \
        sxx = fmaf(x.x, x.x, sxx); sxx = fmaf(x.y, x.y, sxx);                 \
        sxx = fmaf(x.z, x.z, sxx); sxx = fmaf(x.w, x.w, sxx);                 \
        syy = fmaf(y.x, y.x, syy); syy = fmaf(y.y, y.y, syy);                 \
        syy = fmaf(y.z, y.z, syy); syy = fmaf(y.w, y.w, syy);                 \
        sxy = fmaf(x.x, y.x, sxy); sxy = fmaf(x.y, y.y, sxy);                 \
        sxy = fmaf(x.z, y.z, sxy); sxy = fmaf(x.w, y.w, sxy);                 \
    } while (0)

    // vmcnt accounting: entering STEP(k), pairs for slots k..k+AHEAD-1 are
    // outstanding (12 ops). ISSUE(k+AHEAD) makes it 14; vmcnt(12) retires the
    // oldest pair (slot k). Tail (k>9): no issue, outstanding = 2*(16-k),
    // wait 2*(15-k). Only VMEM ops in the loop are these DMAs, so counts are
    // exact.
#define VMN(k) (((k) + AHEAD < PER_THREAD) ? (2 * AHEAD) : (2 * (PER_THREAD - 1 - (k))))
#define STEP(k)                                                               \
    do {                                                                      \
        ISSUE((k) + AHEAD);                                                   \
        wait_vmcnt<VMN(k)>();                                                 \
        CONSUME(k);                                                           \
    } while (0)

    ISSUE(0); ISSUE(1); ISSUE(2); ISSUE(3); ISSUE(4); ISSUE(5);
    STEP(0);  STEP(1);  STEP(2);  STEP(3);
    STEP(4);  STEP(5);  STEP(6);  STEP(7);
    STEP(8);  STEP(9);  STEP(10); STEP(11);
    STEP(12); STEP(13); STEP(14); STEP(15);

#undef STEP
#undef VMN
#undef CONSUME
#undef ISSUE

    // 64-lane wave reduction
    #pragma unroll
    for (int off = 32; off > 0; off >>= 1) {
        sx  += __shfl_down(sx,  off);
        sy  += __shfl_down(sy,  off);
        sxx += __shfl_down(sxx, off);
        syy += __shfl_down(syy, off);
        sxy += __shfl_down(sxy, off);
    }

    __shared__ float red[4][5];
    if (lane == 0) {
        red[wave][0] = sx;  red[wave][1] = sy;  red[wave][2] = sxx;
        red[wave][3] = syy; red[wave][4] = sxy;
    }
    __syncthreads();

    if (threadIdx.x == 0) {
        float t0 = red[0][0] + red[1][0] + red[2][0] + red[3][0];
        float t1 = red[0][1] + red[1][1] + red[2][1] + red[3][1];
        float t2 = red[0][2] + red[1][2] + red[2][2] + red[3][2];
        float t3 = red[0][3] + red[1][3] + red[2][3] + red[3][3];
        float t4 = red[0][4] + red[1][4] + red[2][4] + red[3][4];
        float* dst = partial + ((size_t)row * SEGS + seg) * 5;
        dst[0] = t0; dst[1] = t1; dst[2] = t2; dst[3] = t3; dst[4] = t4;
    }
}

// Single block: one thread per row combines its SEGS partials in double,
// computes (1 - ccc), then block-reduces the mean.
__global__ __launch_bounds__(512) void ccc_final_kernel(
    const float* __restrict__ partial,
    float* __restrict__ out,
    int B, int T)
{
    float loss_sum = 0.f;
    for (int b = threadIdx.x; b < B; b += 512) {
        double tsx = 0, tsy = 0, tsxx = 0, tsyy = 0, tsxy = 0;
        const float* src = partial + (size_t)b * SEGS * 5;
        #pragma unroll
        for (int s = 0; s < SEGS; ++s) {
            tsx  += src[s * 5 + 0];
            tsy  += src[s * 5 + 1];
            tsxx += src[s * 5 + 2];
            tsyy += src[s * 5 + 3];
            tsxy += src[s * 5 + 4];
        }
        const double inv = 1.0 / (double)T;
        const double mx = tsx * inv;
        const double my = tsy * inv;
        const double vx = tsxx * inv - mx * mx;
        const double vy = tsyy * inv - my * my;
        const double cov = tsxy * inv - mx * my;
        const double d = mx - my;
        const double ccc = 2.0 * cov / (vx + vy + d * d + CCC_EPS);
        loss_sum += (float)(1.0 - ccc);
    }

    #pragma unroll
    for (int off = 32; off > 0; off >>= 1) loss_sum += __shfl_down(loss_sum, off);

    __shared__ float red[8];
    const int wave = threadIdx.x >> 6;
    const int lane = threadIdx.x & 63;
    if (lane == 0) red[wave] = loss_sum;
    __syncthreads();
    if (threadIdx.x == 0) {
        float t = 0.f;
        #pragma unroll
        for (int w = 0; w < 8; ++w) t += red[w];
        out[0] = t / (float)B;
    }
}

extern "C" void kernel_launch(void* const* d_in, const int* in_sizes, int n_in,
                              void* d_out, int out_size, void* d_ws, size_t ws_size,
                              hipStream_t stream) {
    const float* preds  = (const float*)d_in[0];
    const float* labels = (const float*)d_in[1];
    float* out = (float*)d_out;

    const int T = 65536;
    const int B = in_sizes[0] / T;   // 512

    float* partial = (float*)d_ws;   // B*SEGS*5 floats

    ccc_partial_kernel<<<B * SEGS, TPB, 0, stream>>>(preds, labels, partial, T);
    ccc_final_kernel<<<1, 512, 0, stream>>>(partial, out, B, T);
}